// Round 7
// baseline (208.303 us; speedup 1.0000x reference)
//
#include <hip/hip_runtime.h>
#include <hip/hip_bf16.h>

// MoE: B=4,T=2048,D=512,E=8,H=512,K=2.  N=8192 tokens.
// v7: 64-token M-blocked tile with 1024-thread (16-wave) blocks:
// 4 waves/SIMD latency hiding + halved B traffic. B-prefetch and bias
// loads hoisted above the staging barrier. pack+gate merged into k_prep.

typedef __bf16 bf16x8 __attribute__((ext_vector_type(8)));
typedef float  f32x4  __attribute__((ext_vector_type(4)));

#define N_TOK 8192
#define D_IN  512
#define N_EXP 8
#define H_DIM 512
#define TILE  64

static __device__ __forceinline__ unsigned short f2bf(float f) {
    union { float f; unsigned u; } v; v.f = f;
    unsigned r = v.u + 0x7FFFu + ((v.u >> 16) & 1u);   // RNE
    return (unsigned short)(r >> 16);
}
static __device__ __forceinline__ float bf2f(unsigned short h) {
    union { unsigned u; float f; } v; v.u = ((unsigned)h) << 16; return v.f;
}

// Merged prep: blocks 0..2047 pack W1/W2 into MFMA B-fragment layout;
// blocks 2048..2303 run the gate (top-2 + softmax).
__global__ void __launch_bounds__(256) k_prep(const float* __restrict__ x,
                                              const float* __restrict__ Wg,
                                              const float* __restrict__ bg,
                                              const float* __restrict__ W1,
                                              const float* __restrict__ W2,
                                              unsigned short* __restrict__ w1f,
                                              unsigned short* __restrict__ w2f,
                                              unsigned char* __restrict__ sel,
                                              float2* __restrict__ w2) {
    __shared__ float t[32][65];
    __shared__ float part[32][8][8];
    __shared__ float lg[32][8];
    int b = blockIdx.x;
    int tid = threadIdx.x;
    if (b < 2048) {
        // ---- pack: out[((e*32+cb)*16+kc)*512 + lane*8 + j] ----
        int z = b >> 7, rem = b & 127;
        int bx = rem & 7, kc = rem >> 3;
        int e = z & 7;
        const float* in = (z < 8) ? W1 : W2;
        unsigned short* out = (z < 8) ? w1f : w2f;
        const float* src = in + ((size_t)e * 512 + kc * 32) * 512 + bx * 64;
        int r = tid >> 3, cq = (tid & 7) * 8;
        float4 v0 = *(const float4*)(src + (size_t)r * 512 + cq);
        float4 v1 = *(const float4*)(src + (size_t)r * 512 + cq + 4);
        t[r][cq + 0] = v0.x; t[r][cq + 1] = v0.y; t[r][cq + 2] = v0.z; t[r][cq + 3] = v0.w;
        t[r][cq + 4] = v1.x; t[r][cq + 5] = v1.y; t[r][cq + 6] = v1.z; t[r][cq + 7] = v1.w;
        __syncthreads();
        int g = tid >> 6, lane = tid & 63;
        int l15 = lane & 15, l4 = lane >> 4;
        unsigned v[4];
        #pragma unroll
        for (int j = 0; j < 4; ++j) {
            unsigned lo = f2bf(t[l4 * 8 + 2 * j    ][g * 16 + l15]);
            unsigned hi = f2bf(t[l4 * 8 + 2 * j + 1][g * 16 + l15]);
            v[j] = lo | (hi << 16);
        }
        size_t dst = (((size_t)(e * 32 + bx * 4 + g) * 16 + kc) * 512) + lane * 8;
        *(uint4*)(out + dst) = make_uint4(v[0], v[1], v[2], v[3]);
    } else {
        // ---- gate: thread (t,c) owns 64-elem chunk c of token t ----
        int gb = b - 2048;
        int tt = tid >> 3, c = tid & 7;
        int n = gb * 32 + tt;
        const float4* xr = (const float4*)(x + (size_t)n * D_IN + c * 64);
        float acc[8];
        #pragma unroll
        for (int e = 0; e < 8; ++e) acc[e] = 0.f;
        #pragma unroll
        for (int j4 = 0; j4 < 16; ++j4) {
            float4 v = xr[j4];
            int k = c * 64 + j4 * 4;
            float xv[4] = {v.x, v.y, v.z, v.w};
            #pragma unroll
            for (int u = 0; u < 4; ++u) {
                float4 wlo = *(const float4*)(Wg + (size_t)(k + u) * 8);
                float4 whi = *(const float4*)(Wg + (size_t)(k + u) * 8 + 4);
                acc[0] += xv[u] * wlo.x; acc[1] += xv[u] * wlo.y;
                acc[2] += xv[u] * wlo.z; acc[3] += xv[u] * wlo.w;
                acc[4] += xv[u] * whi.x; acc[5] += xv[u] * whi.y;
                acc[6] += xv[u] * whi.z; acc[7] += xv[u] * whi.w;
            }
        }
        #pragma unroll
        for (int e = 0; e < 8; ++e) part[tt][c][e] = acc[e];
        __syncthreads();
        {
            float f = bg[c];
            #pragma unroll
            for (int cc = 0; cc < 8; ++cc) f += part[tt][cc][c];
            lg[tt][c] = f;
        }
        __syncthreads();
        if (c == 0) {
            float best = lg[tt][0]; int i1 = 0;
            #pragma unroll
            for (int j = 1; j < 8; ++j) { float v = lg[tt][j]; if (v > best) { best = v; i1 = j; } }
            float best2 = -1e30f; int i2 = 0;
            #pragma unroll
            for (int j = 0; j < 8; ++j) {
                if (j == i1) continue;
                float v = lg[tt][j]; if (v > best2) { best2 = v; i2 = j; }
            }
            float e2 = expf(best2 - best);
            float w0 = 1.0f / (1.0f + e2);
            sel[n] = (unsigned char)(i1 | (i2 << 4));
            w2[n] = make_float2(w0, 1.0f - w0);
        }
    }
}

// Build per-expert compacted token lists; deterministic ballot/prefix scan.
// lists entry = (token<<1) | slot  (slot 0 = top1, 1 = top2).
__global__ void __launch_bounds__(1024) k_build(const unsigned char* __restrict__ sel,
                                                const float2* __restrict__ w2,
                                                int* __restrict__ counts,
                                                int* __restrict__ lists,
                                                float* __restrict__ wgts) {
    int e = blockIdx.x;
    __shared__ int wave_tot[16], wave_base[16];
    int tid = threadIdx.x;
    int lane = tid & 63, wv = tid >> 6;
    int base = 0;
    for (int c0 = 0; c0 < N_TOK; c0 += 1024) {
        int n = c0 + tid;
        unsigned char s = sel[n];
        bool f1 = ((s & 15) == e);
        bool f = f1 || ((s >> 4) == e);
        unsigned long long mask = __ballot(f);
        int prefix = __popcll(mask & ((1ull << lane) - 1ull));
        if (lane == 0) wave_tot[wv] = __popcll(mask);
        __syncthreads();
        if (tid < 16) {
            int wb = 0;
            for (int i = 0; i < tid; ++i) wb += wave_tot[i];
            wave_base[tid] = wb;
        }
        __syncthreads();
        if (f) {
            int pos = base + wave_base[wv] + prefix;
            lists[e * N_TOK + pos] = (n << 1) | (f1 ? 0 : 1);
            float2 w = w2[n];
            wgts[e * N_TOK + pos] = f1 ? w.x : w.y;
        }
        base += wave_base[15] + wave_tot[15];
        __syncthreads();
    }
    if (tid == 0) counts[e] = base;
}

// Fused 2-layer expert FFN, 64-token tile, 1024 thr = 16 waves.
// Wave w owns output cols [w*32, w*32+32).  Two 32-row sub-tiles (A: rows
// 0-31 in ldsA, B: rows 32-63 in ldsB) register-blocked per B-fragment.
// Flat grid: e = blk&7 (-> XCD e), tile = blk>>3.
template <bool SLOT>
__global__ void __launch_bounds__(1024, 4)
k_experts(const float* __restrict__ x,
          const unsigned short* __restrict__ w1f, const float* __restrict__ b1,
          const unsigned short* __restrict__ w2f, const float* __restrict__ b2,
          const int* __restrict__ counts, const int* __restrict__ lists,
          const float* __restrict__ wgts,
          unsigned short* __restrict__ ybuf, float* __restrict__ out) {
    __shared__ unsigned short ldsA[32 * D_IN];   // 32 KiB
    __shared__ unsigned short ldsB[32 * D_IN];   // 32 KiB
    __shared__ int   tl[TILE];
    __shared__ float wl[TILE];

    int b = blockIdx.x;
    int e = b & 7;
    int tile = b >> 3;
    int cnt = counts[e];
    int row0 = tile * TILE;
    if (row0 >= cnt) return;
    int rv = min(TILE, cnt - row0);

    int tid = threadIdx.x;
    int lane = tid & 63;
    int wid = tid >> 6;          // 0..15
    int cw = wid * 32;
    int l15 = lane & 15, l4 = lane >> 4;

    if (tid < TILE) {
        int v = 0; float w = 0.f;
        if (tid < rv) {
            v = lists[e * N_TOK + row0 + tid];
            w = wgts [e * N_TOK + row0 + tid];
        }
        tl[tid] = v; wl[tid] = w;
    }

    // hoisted (LDS-independent) loads: layer-1 B prologue + biases
    const unsigned short* w1base = w1f + ((size_t)(e * 32 + wid * 2) * 16) * 512 + (size_t)lane * 8;
    const unsigned short* w2base = w2f + ((size_t)(e * 32 + wid * 2) * 16) * 512 + (size_t)lane * 8;
    bf16x8 bb[4][2];
    #pragma unroll
    for (int n = 0; n < 2; ++n) {
        bb[0][n] = *(const bf16x8*)(w1base + (n * 16 + 0) * 512);
        bb[1][n] = *(const bf16x8*)(w1base + (n * 16 + 1) * 512);
        bb[2][n] = *(const bf16x8*)(w1base + (n * 16 + 2) * 512);
    }
    float bv1[2], bv2[2];
    #pragma unroll
    for (int n = 0; n < 2; ++n) {
        bv1[n] = b1[e * H_DIM + cw + n * 16 + l15];
        bv2[n] = b2[e * H_DIM + cw + n * 16 + l15];
    }
    __syncthreads();   // tl/wl visible

    // ---- stage gathered X (f32 -> bf16, swizzled): rows 0-31 -> ldsA,
    //      rows 32-63 -> ldsB ----
    #pragma unroll
    for (int it = 0; it < 8; ++it) {
        int idx = tid + it * 1024;           // 8192 float4-groups
        int r = idx >> 7, c4 = idx & 127;
        float4 v = make_float4(0.f, 0.f, 0.f, 0.f);
        if (r < rv)
            v = ((const float4*)(x + (size_t)(tl[r] >> 1) * D_IN))[c4];
        unsigned lo = (unsigned)f2bf(v.x) | ((unsigned)f2bf(v.y) << 16);
        unsigned hi = (unsigned)f2bf(v.z) | ((unsigned)f2bf(v.w) << 16);
        int rr = r & 31;
        int off = (rr * 1024 + c4 * 8) ^ ((rr & 7) << 4);
        char* base = (r < 32) ? (char*)ldsA : (char*)ldsB;
        *(uint2*)(base + off) = make_uint2(lo, hi);
    }
    __syncthreads();

    f32x4 accA[2][2], accB[2][2];

    // ================= layer 1: H = gelu(X @ W1^T + b1) =================
    #pragma unroll
    for (int n = 0; n < 2; ++n)
        #pragma unroll
        for (int m = 0; m < 2; ++m) {
            accA[m][n] = f32x4{bv1[n], bv1[n], bv1[n], bv1[n]};
            accB[m][n] = f32x4{bv1[n], bv1[n], bv1[n], bv1[n]};
        }
    #pragma unroll
    for (int kc = 0; kc < 16; ++kc) {
        if (kc + 3 < 16) {
            #pragma unroll
            for (int n = 0; n < 2; ++n)
                bb[(kc + 3) & 3][n] = *(const bf16x8*)(w1base + (n * 16 + kc + 3) * 512);
        }
        int k0 = kc * 32 + l4 * 8;
        bf16x8 aA[2], aB[2];
        #pragma unroll
        for (int m = 0; m < 2; ++m) {
            int row = m * 16 + l15;
            int off = (row * 1024 + k0 * 2) ^ ((row & 7) << 4);
            aA[m] = *(const bf16x8*)((const char*)ldsA + off);
            aB[m] = *(const bf16x8*)((const char*)ldsB + off);
        }
        #pragma unroll
        for (int n = 0; n < 2; ++n)
            #pragma unroll
            for (int m = 0; m < 2; ++m) {
                accA[m][n] = __builtin_amdgcn_mfma_f32_16x16x32_bf16(aA[m], bb[kc & 3][n], accA[m][n], 0, 0, 0);
                accB[m][n] = __builtin_amdgcn_mfma_f32_16x16x32_bf16(aB[m], bb[kc & 3][n], accB[m][n], 0, 0, 0);
            }
    }

    // layer-2 B prologue (LDS-independent) issued before the gelu barrier
    #pragma unroll
    for (int n = 0; n < 2; ++n) {
        bb[0][n] = *(const bf16x8*)(w2base + (n * 16 + 0) * 512);
        bb[1][n] = *(const bf16x8*)(w2base + (n * 16 + 1) * 512);
        bb[2][n] = *(const bf16x8*)(w2base + (n * 16 + 2) * 512);
    }
    __syncthreads();   // all waves done reading X

    // gelu (exact) + write H back (swizzled)
    #pragma unroll
    for (int m = 0; m < 2; ++m)
        #pragma unroll
        for (int n = 0; n < 2; ++n)
            #pragma unroll
            for (int r = 0; r < 4; ++r) {
                int row = m * 16 + l4 * 4 + r;
                int col = cw + n * 16 + l15;
                int off = (row * 1024 + col * 2) ^ ((row & 7) << 4);
                float vA = accA[m][n][r];
                float gA = 0.5f * vA * (1.0f + erff(vA * 0.70710678118654752f));
                *(unsigned short*)((char*)ldsA + off) = f2bf(gA);
                float vB = accB[m][n][r];
                float gB = 0.5f * vB * (1.0f + erff(vB * 0.70710678118654752f));
                *(unsigned short*)((char*)ldsB + off) = f2bf(gB);
            }
    __syncthreads();

    // ================= layer 2: Y = H @ W2^T + b2 =================
    #pragma unroll
    for (int n = 0; n < 2; ++n)
        #pragma unroll
        for (int m = 0; m < 2; ++m) {
            accA[m][n] = f32x4{bv2[n], bv2[n], bv2[n], bv2[n]};
            accB[m][n] = f32x4{bv2[n], bv2[n], bv2[n], bv2[n]};
        }
    #pragma unroll
    for (int kc = 0; kc < 16; ++kc) {
        if (kc + 3 < 16) {
            #pragma unroll
            for (int n = 0; n < 2; ++n)
                bb[(kc + 3) & 3][n] = *(const bf16x8*)(w2base + (n * 16 + kc + 3) * 512);
        }
        int k0 = kc * 32 + l4 * 8;
        bf16x8 aA[2], aB[2];
        #pragma unroll
        for (int m = 0; m < 2; ++m) {
            int row = m * 16 + l15;
            int off = (row * 1024 + k0 * 2) ^ ((row & 7) << 4);
            aA[m] = *(const bf16x8*)((const char*)ldsA + off);
            aB[m] = *(const bf16x8*)((const char*)ldsB + off);
        }
        #pragma unroll
        for (int n = 0; n < 2; ++n)
            #pragma unroll
            for (int m = 0; m < 2; ++m) {
                accA[m][n] = __builtin_amdgcn_mfma_f32_16x16x32_bf16(aA[m], bb[kc & 3][n], accA[m][n], 0, 0, 0);
                accB[m][n] = __builtin_amdgcn_mfma_f32_16x16x32_bf16(aB[m], bb[kc & 3][n], accB[m][n], 0, 0, 0);
            }
    }

    if (SLOT) {
        __syncthreads();
        // y = w * acc -> bf16 into LDS (linear layout)
        #pragma unroll
        for (int m = 0; m < 2; ++m)
            #pragma unroll
            for (int n = 0; n < 2; ++n)
                #pragma unroll
                for (int r = 0; r < 4; ++r) {
                    int row = m * 16 + l4 * 4 + r;
                    int col = cw + n * 16 + l15;
                    ldsA[row * 512 + col] = f2bf(accA[m][n][r] * wl[row]);
                    ldsB[row * 512 + col] = f2bf(accB[m][n][r] * wl[row + 32]);
                }
        __syncthreads();
        // coalesced write-out: wave w handles rows w*4 .. w*4+3 (of 64)
        #pragma unroll
        for (int rr = 0; rr < 4; ++rr) {
            int row = wid * 4 + rr;
            if (row < rv) {
                int v = tl[row];
                const unsigned short* src = (row < 32) ? ldsA : ldsB;
                uint4 d = *(uint4*)((char*)src + (row & 31) * 1024 + lane * 16);
                *(uint4*)(ybuf + (size_t)v * H_DIM + lane * 8) = d;
            }
        }
    } else {
        #pragma unroll
        for (int m = 0; m < 2; ++m)
            #pragma unroll
            for (int r = 0; r < 4; ++r) {
                int rowA = m * 16 + l4 * 4 + r;
                int rowB = rowA + 32;
                #pragma unroll
                for (int n = 0; n < 2; ++n) {
                    int col = cw + n * 16 + l15;
                    if (rowA < rv)
                        atomicAdd(out + (size_t)(tl[rowA] >> 1) * H_DIM + col, wl[rowA] * accA[m][n][r]);
                    if (rowB < rv)
                        atomicAdd(out + (size_t)(tl[rowB] >> 1) * H_DIM + col, wl[rowB] * accB[m][n][r]);
                }
            }
    }
}

// out[n][h] = yb[2n][h] + yb[2n+1][h]   (bf16 -> f32)
__global__ void __launch_bounds__(256) k_combine(const unsigned short* __restrict__ yb,
                                                 float* __restrict__ out) {
    int gid = blockIdx.x * 256 + threadIdx.x;
    int n = gid >> 6;
    int h0 = (gid & 63) * 8;
    const unsigned short* r0 = yb + ((size_t)2 * n) * H_DIM + h0;
    uint4 a = *(const uint4*)r0;
    uint4 b = *(const uint4*)(r0 + H_DIM);
    float o[8];
    unsigned ua[4] = {a.x, a.y, a.z, a.w}, ub[4] = {b.x, b.y, b.z, b.w};
    #pragma unroll
    for (int j = 0; j < 4; ++j) {
        o[2 * j]     = bf2f((unsigned short)(ua[j] & 0xFFFF)) + bf2f((unsigned short)(ub[j] & 0xFFFF));
        o[2 * j + 1] = bf2f((unsigned short)(ua[j] >> 16))    + bf2f((unsigned short)(ub[j] >> 16));
    }
    float* dst = out + (size_t)n * H_DIM + h0;
    *(float4*)dst       = make_float4(o[0], o[1], o[2], o[3]);
    *(float4*)(dst + 4) = make_float4(o[4], o[5], o[6], o[7]);
}

extern "C" void kernel_launch(void* const* d_in, const int* in_sizes, int n_in,
                              void* d_out, int out_size, void* d_ws, size_t ws_size,
                              hipStream_t stream) {
    (void)in_sizes; (void)n_in;
    const float* x  = (const float*)d_in[0];
    const float* Wg = (const float*)d_in[1];
    const float* bg = (const float*)d_in[2];
    const float* W1 = (const float*)d_in[3];
    const float* b1 = (const float*)d_in[4];
    const float* W2 = (const float*)d_in[5];
    const float* b2 = (const float*)d_in[6];
    float* out = (float*)d_out;

    char* ws = (char*)d_ws;
    unsigned short* w1f = (unsigned short*)(ws);                       // 4 MiB
    unsigned short* w2f = (unsigned short*)(ws + (4u << 20));          // 4 MiB
    unsigned short* ybuf= (unsigned short*)(ws + (8u << 20));          // 16 MiB
    char* tail = ws + (24u << 20);
    int*   counts = (int*)(tail);                                      // 32 B
    int*   lists  = (int*)(tail + 256);                                // 256 KiB
    float* wgts   = (float*)(tail + 256 + 262144);                     // 256 KiB
    unsigned char* sel = (unsigned char*)(tail + 256 + 524288);        // 8 KiB
    float2* w2g   = (float2*)(tail + 256 + 532480);                    // 64 KiB
    size_t need = (24u << 20) + 256 + 532480 + 65536;

    bool slot = ws_size >= need;
    if (!slot) {
        // compact fallback (atomic epilogue): w1f, w2f, tail
        tail = ws + (8u << 20);
        counts = (int*)(tail);
        lists  = (int*)(tail + 256);
        wgts   = (float*)(tail + 256 + 262144);
        sel    = (unsigned char*)(tail + 256 + 524288);
        w2g    = (float2*)(tail + 256 + 532480);
        hipMemsetAsync(out, 0, (size_t)out_size * sizeof(float), stream);
    }

    k_prep<<<dim3(2048 + N_TOK / 32), dim3(256), 0, stream>>>(
        x, Wg, bg, W1, W2, w1f, w2f, sel, w2g);
    k_build<<<dim3(N_EXP), dim3(1024), 0, stream>>>(sel, w2g, counts, lists, wgts);
    if (slot) {
        k_experts<true><<<dim3(1024), dim3(1024), 0, stream>>>(
            x, w1f, b1, w2f, b2, counts, lists, wgts, ybuf, out);
        k_combine<<<dim3(N_TOK * 64 / 256), dim3(256), 0, stream>>>(ybuf, out);
    } else {
        k_experts<false><<<dim3(1024), dim3(1024), 0, stream>>>(
            x, w1f, b1, w2f, b2, counts, lists, wgts, ybuf, out);
    }
}

// Round 8
// 175.344 us; speedup vs baseline: 1.1880x; 1.1880x over previous
//
#include <hip/hip_runtime.h>
#include <hip/hip_bf16.h>

// MoE: B=4,T=2048,D=512,E=8,H=512,K=2.  N=8192 tokens.
// v8: de-fused expert layers (k_l1: X@W1+gelu -> H ; k_l2: H@W2 -> ybuf),
// 64-token x 256-col tiles => 2 working blocks/CU under XCD affinity with
// TILE=64-level weight traffic. H (bf16) stays L2-resident per XCD.
// Separate k_pack / k_gate again (R7's merged kernel strangled VGPRs).

typedef __bf16 bf16x8 __attribute__((ext_vector_type(8)));
typedef float  f32x4  __attribute__((ext_vector_type(4)));

#define N_TOK 8192
#define D_IN  512
#define N_EXP 8
#define H_DIM 512

static __device__ __forceinline__ unsigned short f2bf(float f) {
    union { float f; unsigned u; } v; v.f = f;
    unsigned r = v.u + 0x7FFFu + ((v.u >> 16) & 1u);   // RNE
    return (unsigned short)(r >> 16);
}
static __device__ __forceinline__ float bf2f(unsigned short h) {
    union { unsigned u; float f; } v; v.u = ((unsigned)h) << 16; return v.f;
}
static __device__ __forceinline__ float gelu_exact(float v) {
    return 0.5f * v * (1.0f + erff(v * 0.70710678118654752f));
}

// Pack W1 and W2 (f32 [E][512][512]) into MFMA B-fragment-linear bf16:
// out[((e*32+cb)*16+kc)*512 + lane*8 + j] = bf16(W[e][kc*32+(lane>>4)*8+j][cb*16+(lane&15)])
__global__ void __launch_bounds__(256) k_pack(const float* __restrict__ W1,
                                              const float* __restrict__ W2,
                                              unsigned short* __restrict__ w1f,
                                              unsigned short* __restrict__ w2f) {
    __shared__ float t[32][65];
    int z = blockIdx.z;
    int e = z & 7;
    const float* in = (z < 8) ? W1 : W2;
    unsigned short* out = (z < 8) ? w1f : w2f;
    int cb0 = blockIdx.x * 4;
    int kc  = blockIdx.y;
    const float* src = in + ((size_t)e * 512 + kc * 32) * 512 + blockIdx.x * 64;
    int tid = threadIdx.x;
    int r = tid >> 3, cq = (tid & 7) * 8;
    float4 v0 = *(const float4*)(src + (size_t)r * 512 + cq);
    float4 v1 = *(const float4*)(src + (size_t)r * 512 + cq + 4);
    t[r][cq + 0] = v0.x; t[r][cq + 1] = v0.y; t[r][cq + 2] = v0.z; t[r][cq + 3] = v0.w;
    t[r][cq + 4] = v1.x; t[r][cq + 5] = v1.y; t[r][cq + 6] = v1.z; t[r][cq + 7] = v1.w;
    __syncthreads();
    int g = tid >> 6, lane = tid & 63;
    int l15 = lane & 15, l4 = lane >> 4;
    unsigned v[4];
    #pragma unroll
    for (int j = 0; j < 4; ++j) {
        unsigned lo = f2bf(t[l4 * 8 + 2 * j    ][g * 16 + l15]);
        unsigned hi = f2bf(t[l4 * 8 + 2 * j + 1][g * 16 + l15]);
        v[j] = lo | (hi << 16);
    }
    size_t dst = (((size_t)(e * 32 + cb0 + g) * 16 + kc) * 512) + lane * 8;
    *(uint4*)(out + dst) = make_uint4(v[0], v[1], v[2], v[3]);
}

// Gate: block = 256 thr = 32 tokens. Thread (t,c) owns 64-elem chunk c of
// token t's row: x read ONCE, coalesced. Partial dots -> LDS reduce -> top-2.
__global__ void __launch_bounds__(256) k_gate(const float* __restrict__ x,
                                              const float* __restrict__ Wg,
                                              const float* __restrict__ bg,
                                              unsigned char* __restrict__ sel,
                                              float2* __restrict__ w2) {
    __shared__ float part[32][8][8];
    __shared__ float lg[32][8];
    int tid = threadIdx.x;
    int t = tid >> 3, c = tid & 7;
    int n = blockIdx.x * 32 + t;
    const float4* xr = (const float4*)(x + (size_t)n * D_IN + c * 64);
    float acc[8];
    #pragma unroll
    for (int e = 0; e < 8; ++e) acc[e] = 0.f;
    #pragma unroll
    for (int j4 = 0; j4 < 16; ++j4) {
        float4 v = xr[j4];
        int k = c * 64 + j4 * 4;
        float xv[4] = {v.x, v.y, v.z, v.w};
        #pragma unroll
        for (int u = 0; u < 4; ++u) {
            float4 wlo = *(const float4*)(Wg + (size_t)(k + u) * 8);
            float4 whi = *(const float4*)(Wg + (size_t)(k + u) * 8 + 4);
            acc[0] += xv[u] * wlo.x; acc[1] += xv[u] * wlo.y;
            acc[2] += xv[u] * wlo.z; acc[3] += xv[u] * wlo.w;
            acc[4] += xv[u] * whi.x; acc[5] += xv[u] * whi.y;
            acc[6] += xv[u] * whi.z; acc[7] += xv[u] * whi.w;
        }
    }
    #pragma unroll
    for (int e = 0; e < 8; ++e) part[t][c][e] = acc[e];
    __syncthreads();
    {
        float f = bg[c];
        #pragma unroll
        for (int cc = 0; cc < 8; ++cc) f += part[t][cc][c];
        lg[t][c] = f;
    }
    __syncthreads();
    if (c == 0) {
        float best = lg[t][0]; int i1 = 0;
        #pragma unroll
        for (int j = 1; j < 8; ++j) { float v = lg[t][j]; if (v > best) { best = v; i1 = j; } }
        float best2 = -1e30f; int i2 = 0;
        #pragma unroll
        for (int j = 0; j < 8; ++j) {
            if (j == i1) continue;
            float v = lg[t][j]; if (v > best2) { best2 = v; i2 = j; }
        }
        float tt = expf(best2 - best);
        float w0 = 1.0f / (1.0f + tt);
        sel[n] = (unsigned char)(i1 | (i2 << 4));
        w2[n] = make_float2(w0, 1.0f - w0);
    }
}

// Build per-expert compacted token lists; deterministic ballot/prefix scan.
// lists entry = (token<<1) | slot  (slot 0 = top1, 1 = top2).
__global__ void __launch_bounds__(1024) k_build(const unsigned char* __restrict__ sel,
                                                const float2* __restrict__ w2,
                                                int* __restrict__ counts,
                                                int* __restrict__ lists,
                                                float* __restrict__ wgts) {
    int e = blockIdx.x;
    __shared__ int wave_tot[16], wave_base[16];
    int tid = threadIdx.x;
    int lane = tid & 63, wv = tid >> 6;
    int base = 0;
    for (int c0 = 0; c0 < N_TOK; c0 += 1024) {
        int n = c0 + tid;
        unsigned char s = sel[n];
        bool f1 = ((s & 15) == e);
        bool f = f1 || ((s >> 4) == e);
        unsigned long long mask = __ballot(f);
        int prefix = __popcll(mask & ((1ull << lane) - 1ull));
        if (lane == 0) wave_tot[wv] = __popcll(mask);
        __syncthreads();
        if (tid < 16) {
            int wb = 0;
            for (int i = 0; i < tid; ++i) wb += wave_tot[i];
            wave_base[tid] = wb;
        }
        __syncthreads();
        if (f) {
            int pos = base + wave_base[wv] + prefix;
            lists[e * N_TOK + pos] = (n << 1) | (f1 ? 0 : 1);
            float2 w = w2[n];
            wgts[e * N_TOK + pos] = f1 ? w.x : w.y;
        }
        base += wave_base[15] + wave_tot[15];
        __syncthreads();
    }
    if (tid == 0) counts[e] = base;
}

// ---------- Layer 1: H[gb+row][col] = gelu(X @ W1 + b1), 64x256 tiles ----------
// grid flat: e = b&7 (XCD affinity), tile = (b>>3)>>1, ch = (b>>3)&1.
// 512 thr = 8 waves; wave owns 32 cols (2 frags); 4 m-frags (64 rows).
__global__ void __launch_bounds__(512, 4)
k_l1(const float* __restrict__ x,
     const unsigned short* __restrict__ w1f, const float* __restrict__ b1,
     const int* __restrict__ counts, const int* __restrict__ lists,
     unsigned short* __restrict__ hbuf) {
    __shared__ unsigned short lds[64 * D_IN];   // 64 KiB
    __shared__ int tl[64];

    int b = blockIdx.x;
    int e = b & 7;
    int rest = b >> 3;
    int tile = rest >> 1, ch = rest & 1;
    int cnt = counts[e];
    int row0 = tile * 64;
    if (row0 >= cnt) return;
    int rv = min(64, cnt - row0);
    int gb = row0;
    #pragma unroll
    for (int i = 0; i < 8; ++i) gb += (i < e) ? ((counts[i] + 63) & ~63) : 0;

    int tid = threadIdx.x, lane = tid & 63, wid = tid >> 6;
    int l15 = lane & 15, l4 = lane >> 4;
    if (tid < 64) tl[tid] = (tid < rv) ? lists[e * N_TOK + row0 + tid] : 0;

    const unsigned short* wbase = w1f + ((size_t)(e * 32 + ch * 16 + wid * 2) * 16) * 512 + (size_t)lane * 8;
    bf16x8 bb[3][2];
    #pragma unroll
    for (int n = 0; n < 2; ++n) {
        bb[0][n] = *(const bf16x8*)(wbase + (n * 16 + 0) * 512);
        bb[1][n] = *(const bf16x8*)(wbase + (n * 16 + 1) * 512);
    }
    float bv[2];
    #pragma unroll
    for (int n = 0; n < 2; ++n) bv[n] = b1[e * H_DIM + ch * 256 + wid * 32 + n * 16 + l15];
    __syncthreads();   // tl visible

    // stage gathered X (f32 -> bf16, swizzled) rows 0..63
    #pragma unroll
    for (int it = 0; it < 16; ++it) {
        int idx = tid + it * 512;
        int r = idx >> 7, c4 = idx & 127;
        float4 v = make_float4(0.f, 0.f, 0.f, 0.f);
        if (r < rv)
            v = ((const float4*)(x + (size_t)(tl[r] >> 1) * D_IN))[c4];
        unsigned lo = (unsigned)f2bf(v.x) | ((unsigned)f2bf(v.y) << 16);
        unsigned hi = (unsigned)f2bf(v.z) | ((unsigned)f2bf(v.w) << 16);
        int off = (r * 1024 + c4 * 8) ^ ((r & 7) << 4);
        *(uint2*)((char*)lds + off) = make_uint2(lo, hi);
    }
    __syncthreads();

    f32x4 acc[4][2];
    #pragma unroll
    for (int n = 0; n < 2; ++n)
        #pragma unroll
        for (int m = 0; m < 4; ++m) acc[m][n] = f32x4{bv[n], bv[n], bv[n], bv[n]};

    #pragma unroll
    for (int kc = 0; kc < 16; ++kc) {
        if (kc + 2 < 16) {
            #pragma unroll
            for (int n = 0; n < 2; ++n)
                bb[(kc + 2) % 3][n] = *(const bf16x8*)(wbase + (n * 16 + kc + 2) * 512);
        }
        int k0 = kc * 32 + l4 * 8;
        bf16x8 a[4];
        #pragma unroll
        for (int m = 0; m < 4; ++m) {
            int row = m * 16 + l15;
            int off = (row * 1024 + k0 * 2) ^ ((row & 7) << 4);
            a[m] = *(const bf16x8*)((const char*)lds + off);
        }
        #pragma unroll
        for (int n = 0; n < 2; ++n)
            #pragma unroll
            for (int m = 0; m < 4; ++m)
                acc[m][n] = __builtin_amdgcn_mfma_f32_16x16x32_bf16(a[m], bb[kc % 3][n], acc[m][n], 0, 0, 0);
    }
    __syncthreads();   // done reading A

    // gelu -> lds [64][256] linear
    #pragma unroll
    for (int m = 0; m < 4; ++m)
        #pragma unroll
        for (int n = 0; n < 2; ++n)
            #pragma unroll
            for (int r = 0; r < 4; ++r) {
                int row = m * 16 + l4 * 4 + r;
                int lcol = wid * 32 + n * 16 + l15;
                lds[row * 256 + lcol] = f2bf(gelu_exact(acc[m][n][r]));
            }
    __syncthreads();
    // coalesced H store
    #pragma unroll
    for (int it = 0; it < 4; ++it) {
        int idx = tid + it * 512;
        int row = idx >> 5, g = idx & 31;
        if (row < rv)
            *(uint4*)(hbuf + (size_t)(gb + row) * 512 + ch * 256 + g * 8) =
                *(uint4*)(lds + row * 256 + g * 8);
    }
}

// ---------- Layer 2: y = (H @ W2 + b2) * w -> ybuf slots ----------
template <bool SLOT>
__global__ void __launch_bounds__(512, 4)
k_l2(const unsigned short* __restrict__ hbuf,
     const unsigned short* __restrict__ w2f, const float* __restrict__ b2,
     const int* __restrict__ counts, const int* __restrict__ lists,
     const float* __restrict__ wgts,
     unsigned short* __restrict__ ybuf, float* __restrict__ out) {
    __shared__ unsigned short lds[64 * D_IN];   // 64 KiB
    __shared__ int   tl[64];
    __shared__ float wl[64];

    int b = blockIdx.x;
    int e = b & 7;
    int rest = b >> 3;
    int tile = rest >> 1, ch = rest & 1;
    int cnt = counts[e];
    int row0 = tile * 64;
    if (row0 >= cnt) return;
    int rv = min(64, cnt - row0);
    int gb = row0;
    #pragma unroll
    for (int i = 0; i < 8; ++i) gb += (i < e) ? ((counts[i] + 63) & ~63) : 0;

    int tid = threadIdx.x, lane = tid & 63, wid = tid >> 6;
    int l15 = lane & 15, l4 = lane >> 4;
    if (tid < 64) {
        int v = 0; float w = 0.f;
        if (tid < rv) {
            v = lists[e * N_TOK + row0 + tid];
            w = wgts [e * N_TOK + row0 + tid];
        }
        tl[tid] = v; wl[tid] = w;
    }

    const unsigned short* wbase = w2f + ((size_t)(e * 32 + ch * 16 + wid * 2) * 16) * 512 + (size_t)lane * 8;
    bf16x8 bb[3][2];
    #pragma unroll
    for (int n = 0; n < 2; ++n) {
        bb[0][n] = *(const bf16x8*)(wbase + (n * 16 + 0) * 512);
        bb[1][n] = *(const bf16x8*)(wbase + (n * 16 + 1) * 512);
    }
    float bv[2];
    #pragma unroll
    for (int n = 0; n < 2; ++n) bv[n] = b2[e * H_DIM + ch * 256 + wid * 32 + n * 16 + l15];
    __syncthreads();

    // stage H rows (bf16, contiguous, swizzled)
    #pragma unroll
    for (int it = 0; it < 8; ++it) {
        int idx = tid + it * 512;
        int r = idx >> 6, g = idx & 63;
        uint4 v = make_uint4(0, 0, 0, 0);
        if (r < rv)
            v = *(const uint4*)(hbuf + (size_t)(gb + r) * 512 + g * 8);
        int off = (r * 1024 + g * 16) ^ ((r & 7) << 4);
        *(uint4*)((char*)lds + off) = v;
    }
    __syncthreads();

    f32x4 acc[4][2];
    #pragma unroll
    for (int n = 0; n < 2; ++n)
        #pragma unroll
        for (int m = 0; m < 4; ++m) acc[m][n] = f32x4{bv[n], bv[n], bv[n], bv[n]};

    #pragma unroll
    for (int kc = 0; kc < 16; ++kc) {
        if (kc + 2 < 16) {
            #pragma unroll
            for (int n = 0; n < 2; ++n)
                bb[(kc + 2) % 3][n] = *(const bf16x8*)(wbase + (n * 16 + kc + 2) * 512);
        }
        int k0 = kc * 32 + l4 * 8;
        bf16x8 a[4];
        #pragma unroll
        for (int m = 0; m < 4; ++m) {
            int row = m * 16 + l15;
            int off = (row * 1024 + k0 * 2) ^ ((row & 7) << 4);
            a[m] = *(const bf16x8*)((const char*)lds + off);
        }
        #pragma unroll
        for (int n = 0; n < 2; ++n)
            #pragma unroll
            for (int m = 0; m < 4; ++m)
                acc[m][n] = __builtin_amdgcn_mfma_f32_16x16x32_bf16(a[m], bb[kc % 3][n], acc[m][n], 0, 0, 0);
    }

    if (SLOT) {
        __syncthreads();
        #pragma unroll
        for (int m = 0; m < 4; ++m)
            #pragma unroll
            for (int n = 0; n < 2; ++n)
                #pragma unroll
                for (int r = 0; r < 4; ++r) {
                    int row = m * 16 + l4 * 4 + r;
                    int lcol = wid * 32 + n * 16 + l15;
                    lds[row * 256 + lcol] = f2bf(acc[m][n][r] * wl[row]);
                }
        __syncthreads();
        #pragma unroll
        for (int it = 0; it < 4; ++it) {
            int idx = tid + it * 512;
            int row = idx >> 5, g = idx & 31;
            if (row < rv)
                *(uint4*)(ybuf + (size_t)tl[row] * 512 + ch * 256 + g * 8) =
                    *(uint4*)(lds + row * 256 + g * 8);
        }
    } else {
        #pragma unroll
        for (int m = 0; m < 4; ++m)
            #pragma unroll
            for (int r = 0; r < 4; ++r) {
                int row = m * 16 + l4 * 4 + r;
                if (row < rv) {
                    int t = tl[row] >> 1;
                    float gw = wl[row];
                    #pragma unroll
                    for (int n = 0; n < 2; ++n) {
                        int col = ch * 256 + wid * 32 + n * 16 + l15;
                        atomicAdd(out + (size_t)t * H_DIM + col, gw * acc[m][n][r]);
                    }
                }
            }
    }
}

// out[n][h] = yb[2n][h] + yb[2n+1][h]   (bf16 -> f32)
__global__ void __launch_bounds__(256) k_combine(const unsigned short* __restrict__ yb,
                                                 float* __restrict__ out) {
    int gid = blockIdx.x * 256 + threadIdx.x;
    int n = gid >> 6;
    int h0 = (gid & 63) * 8;
    const unsigned short* r0 = yb + ((size_t)2 * n) * H_DIM + h0;
    uint4 a = *(const uint4*)r0;
    uint4 b = *(const uint4*)(r0 + H_DIM);
    float o[8];
    unsigned ua[4] = {a.x, a.y, a.z, a.w}, ub[4] = {b.x, b.y, b.z, b.w};
    #pragma unroll
    for (int j = 0; j < 4; ++j) {
        o[2 * j]     = bf2f((unsigned short)(ua[j] & 0xFFFF)) + bf2f((unsigned short)(ub[j] & 0xFFFF));
        o[2 * j + 1] = bf2f((unsigned short)(ua[j] >> 16))    + bf2f((unsigned short)(ub[j] >> 16));
    }
    float* dst = out + (size_t)n * H_DIM + h0;
    *(float4*)dst       = make_float4(o[0], o[1], o[2], o[3]);
    *(float4*)(dst + 4) = make_float4(o[4], o[5], o[6], o[7]);
}

extern "C" void kernel_launch(void* const* d_in, const int* in_sizes, int n_in,
                              void* d_out, int out_size, void* d_ws, size_t ws_size,
                              hipStream_t stream) {
    (void)in_sizes; (void)n_in;
    const float* x  = (const float*)d_in[0];
    const float* Wg = (const float*)d_in[1];
    const float* bg = (const float*)d_in[2];
    const float* W1 = (const float*)d_in[3];
    const float* b1 = (const float*)d_in[4];
    const float* W2 = (const float*)d_in[5];
    const float* b2 = (const float*)d_in[6];
    float* out = (float*)d_out;

    char* ws = (char*)d_ws;
    const size_t tail_sz = 256 + 262144 + 262144 + 8192 + 65536;
    size_t need1 = (41ull << 20) + tail_sz;   // full slot path
    size_t need2 = (25ull << 20) + tail_sz;   // de-fused, atomic L2

    unsigned short* w1f = (unsigned short*)(ws);                 // 4 MiB
    unsigned short* w2f = (unsigned short*)(ws + (4ull << 20));  // 4 MiB
    unsigned short* ybuf = nullptr;
    unsigned short* hbuf = nullptr;
    char* tail;
    int mode;
    if (ws_size >= need1) {
        mode = 0;
        ybuf = (unsigned short*)(ws + (8ull << 20));             // 16 MiB
        hbuf = (unsigned short*)(ws + (24ull << 20));            // 17 MiB
        tail = ws + (41ull << 20);
    } else if (ws_size >= need2) {
        mode = 1;
        hbuf = (unsigned short*)(ws + (8ull << 20));             // 17 MiB
        tail = ws + (25ull << 20);
    } else {
        mode = 1;   // last resort: same layout, hope for the best within ws
        hbuf = (unsigned short*)(ws + (8ull << 20));
        tail = ws + (25ull << 20);
    }
    int*   counts = (int*)(tail);
    int*   lists  = (int*)(tail + 256);
    float* wgts   = (float*)(tail + 256 + 262144);
    unsigned char* sel = (unsigned char*)(tail + 256 + 524288);
    float2* w2g   = (float2*)(tail + 256 + 532480);

    if (mode == 1)
        hipMemsetAsync(out, 0, (size_t)out_size * sizeof(float), stream);

    k_pack<<<dim3(8, 16, 16), dim3(256), 0, stream>>>(W1, W2, w1f, w2f);
    k_gate<<<dim3(N_TOK / 32), dim3(256), 0, stream>>>(x, Wg, bg, sel, w2g);
    k_build<<<dim3(N_EXP), dim3(1024), 0, stream>>>(sel, w2g, counts, lists, wgts);
    k_l1<<<dim3(2048), dim3(512), 0, stream>>>(x, w1f, b1, counts, lists, hbuf);
    if (mode == 0) {
        k_l2<true><<<dim3(2048), dim3(512), 0, stream>>>(
            hbuf, w2f, b2, counts, lists, wgts, ybuf, out);
        k_combine<<<dim3(N_TOK * 64 / 256), dim3(256), 0, stream>>>(ybuf, out);
    } else {
        k_l2<false><<<dim3(2048), dim3(512), 0, stream>>>(
            hbuf, w2f, b2, counts, lists, wgts, hbuf /*unused*/, out);
    }
}

// Round 9
// 168.532 us; speedup vs baseline: 1.2360x; 1.0404x over previous
//
#include <hip/hip_runtime.h>
#include <hip/hip_bf16.h>

// MoE: B=4,T=2048,D=512,E=8,H=512,K=2.  N=8192 tokens.
// v9: de-fused expert layers with global_load_lds staging (direct-to-LDS,
// 1 row per wave-instr, source-side XOR swizzle).  Gate re-emits bf16 x.

typedef __bf16 bf16x8 __attribute__((ext_vector_type(8)));
typedef float  f32x4  __attribute__((ext_vector_type(4)));

#define N_TOK 8192
#define D_IN  512
#define N_EXP 8
#define H_DIM 512

static __device__ __forceinline__ unsigned short f2bf(float f) {
    union { float f; unsigned u; } v; v.f = f;
    unsigned r = v.u + 0x7FFFu + ((v.u >> 16) & 1u);   // RNE
    return (unsigned short)(r >> 16);
}
static __device__ __forceinline__ float bf2f(unsigned short h) {
    union { unsigned u; float f; } v; v.u = ((unsigned)h) << 16; return v.f;
}
static __device__ __forceinline__ float gelu_exact(float v) {
    return 0.5f * v * (1.0f + erff(v * 0.70710678118654752f));
}
// direct global->LDS copy, 16B per lane (wave stages 1 KiB row)
static __device__ __forceinline__ void gload_lds16(const void* src, void* lds_dst) {
    __builtin_amdgcn_global_load_lds(
        (const __attribute__((address_space(1))) unsigned int*)src,
        (__attribute__((address_space(3))) unsigned int*)lds_dst, 16, 0, 0);
}

// Pack W1 and W2 (f32 [E][512][512]) into MFMA B-fragment-linear bf16:
// out[((e*32+cb)*16+kc)*512 + lane*8 + j] = bf16(W[e][kc*32+(lane>>4)*8+j][cb*16+(lane&15)])
__global__ void __launch_bounds__(256) k_pack(const float* __restrict__ W1,
                                              const float* __restrict__ W2,
                                              unsigned short* __restrict__ w1f,
                                              unsigned short* __restrict__ w2f) {
    __shared__ float t[32][65];
    int z = blockIdx.z;
    int e = z & 7;
    const float* in = (z < 8) ? W1 : W2;
    unsigned short* out = (z < 8) ? w1f : w2f;
    int cb0 = blockIdx.x * 4;
    int kc  = blockIdx.y;
    const float* src = in + ((size_t)e * 512 + kc * 32) * 512 + blockIdx.x * 64;
    int tid = threadIdx.x;
    int r = tid >> 3, cq = (tid & 7) * 8;
    float4 v0 = *(const float4*)(src + (size_t)r * 512 + cq);
    float4 v1 = *(const float4*)(src + (size_t)r * 512 + cq + 4);
    t[r][cq + 0] = v0.x; t[r][cq + 1] = v0.y; t[r][cq + 2] = v0.z; t[r][cq + 3] = v0.w;
    t[r][cq + 4] = v1.x; t[r][cq + 5] = v1.y; t[r][cq + 6] = v1.z; t[r][cq + 7] = v1.w;
    __syncthreads();
    int g = tid >> 6, lane = tid & 63;
    int l15 = lane & 15, l4 = lane >> 4;
    unsigned v[4];
    #pragma unroll
    for (int j = 0; j < 4; ++j) {
        unsigned lo = f2bf(t[l4 * 8 + 2 * j    ][g * 16 + l15]);
        unsigned hi = f2bf(t[l4 * 8 + 2 * j + 1][g * 16 + l15]);
        v[j] = lo | (hi << 16);
    }
    size_t dst = (((size_t)(e * 32 + cb0 + g) * 16 + kc) * 512) + lane * 8;
    *(uint4*)(out + dst) = make_uint4(v[0], v[1], v[2], v[3]);
}

// Gate: block = 256 thr = 32 tokens. Thread (t,c) owns 64-elem chunk c of
// token t's row: x read ONCE, coalesced. Partial dots -> LDS reduce -> top-2.
// Phase 2: convert the block's 32 rows to bf16 (xbf), coalesced.
__global__ void __launch_bounds__(256) k_gate(const float* __restrict__ x,
                                              const float* __restrict__ Wg,
                                              const float* __restrict__ bg,
                                              unsigned char* __restrict__ sel,
                                              float2* __restrict__ w2,
                                              unsigned short* __restrict__ xbf) {
    __shared__ float part[32][8][8];
    __shared__ float lg[32][8];
    int tid = threadIdx.x;
    int t = tid >> 3, c = tid & 7;
    int n0 = blockIdx.x * 32;
    int n = n0 + t;
    const float4* xr = (const float4*)(x + (size_t)n * D_IN + c * 64);
    float acc[8];
    #pragma unroll
    for (int e = 0; e < 8; ++e) acc[e] = 0.f;
    #pragma unroll
    for (int j4 = 0; j4 < 16; ++j4) {
        float4 v = xr[j4];
        int k = c * 64 + j4 * 4;
        float xv[4] = {v.x, v.y, v.z, v.w};
        #pragma unroll
        for (int u = 0; u < 4; ++u) {
            float4 wlo = *(const float4*)(Wg + (size_t)(k + u) * 8);
            float4 whi = *(const float4*)(Wg + (size_t)(k + u) * 8 + 4);
            acc[0] += xv[u] * wlo.x; acc[1] += xv[u] * wlo.y;
            acc[2] += xv[u] * wlo.z; acc[3] += xv[u] * wlo.w;
            acc[4] += xv[u] * whi.x; acc[5] += xv[u] * whi.y;
            acc[6] += xv[u] * whi.z; acc[7] += xv[u] * whi.w;
        }
    }
    #pragma unroll
    for (int e = 0; e < 8; ++e) part[t][c][e] = acc[e];
    __syncthreads();
    {
        float f = bg[c];
        #pragma unroll
        for (int cc = 0; cc < 8; ++cc) f += part[t][cc][c];
        lg[t][c] = f;
    }
    __syncthreads();
    if (c == 0) {
        float best = lg[t][0]; int i1 = 0;
        #pragma unroll
        for (int j = 1; j < 8; ++j) { float v = lg[t][j]; if (v > best) { best = v; i1 = j; } }
        float best2 = -1e30f; int i2 = 0;
        #pragma unroll
        for (int j = 0; j < 8; ++j) {
            if (j == i1) continue;
            float v = lg[t][j]; if (v > best2) { best2 = v; i2 = j; }
        }
        float tt = expf(best2 - best);
        float w0 = 1.0f / (1.0f + tt);
        sel[n] = (unsigned char)(i1 | (i2 << 4));
        w2[n] = make_float2(w0, 1.0f - w0);
    }
    // phase 2: f32 -> bf16 copy of this block's 32 rows (reads hit L1/L2)
    #pragma unroll
    for (int i = 0; i < 8; ++i) {
        int idx = tid + i * 256;          // 2048 groups of 8 elems
        int r = idx >> 6, g = idx & 63;
        const float* src = x + (size_t)(n0 + r) * D_IN + g * 8;
        float4 a = *(const float4*)src;
        float4 b = *(const float4*)(src + 4);
        unsigned u0 = (unsigned)f2bf(a.x) | ((unsigned)f2bf(a.y) << 16);
        unsigned u1 = (unsigned)f2bf(a.z) | ((unsigned)f2bf(a.w) << 16);
        unsigned u2 = (unsigned)f2bf(b.x) | ((unsigned)f2bf(b.y) << 16);
        unsigned u3 = (unsigned)f2bf(b.z) | ((unsigned)f2bf(b.w) << 16);
        *(uint4*)(xbf + (size_t)(n0 + r) * D_IN + g * 8) = make_uint4(u0, u1, u2, u3);
    }
}

// Build per-expert compacted token lists; deterministic ballot/prefix scan.
// lists entry = (token<<1) | slot  (slot 0 = top1, 1 = top2).
__global__ void __launch_bounds__(1024) k_build(const unsigned char* __restrict__ sel,
                                                const float2* __restrict__ w2,
                                                int* __restrict__ counts,
                                                int* __restrict__ lists,
                                                float* __restrict__ wgts) {
    int e = blockIdx.x;
    __shared__ int wave_tot[16], wave_base[16];
    int tid = threadIdx.x;
    int lane = tid & 63, wv = tid >> 6;
    int base = 0;
    for (int c0 = 0; c0 < N_TOK; c0 += 1024) {
        int n = c0 + tid;
        unsigned char s = sel[n];
        bool f1 = ((s & 15) == e);
        bool f = f1 || ((s >> 4) == e);
        unsigned long long mask = __ballot(f);
        int prefix = __popcll(mask & ((1ull << lane) - 1ull));
        if (lane == 0) wave_tot[wv] = __popcll(mask);
        __syncthreads();
        if (tid < 16) {
            int wb = 0;
            for (int i = 0; i < tid; ++i) wb += wave_tot[i];
            wave_base[tid] = wb;
        }
        __syncthreads();
        if (f) {
            int pos = base + wave_base[wv] + prefix;
            lists[e * N_TOK + pos] = (n << 1) | (f1 ? 0 : 1);
            float2 w = w2[n];
            wgts[e * N_TOK + pos] = f1 ? w.x : w.y;
        }
        base += wave_base[15] + wave_tot[15];
        __syncthreads();
    }
    if (tid == 0) counts[e] = base;
}

// ---------- Layer 1: H = gelu(X @ W1 + b1), 64x256 tiles ----------
// grid flat: e = b&7 (XCD affinity), tile = (b>>3)>>1, ch = (b>>3)&1.
// 512 thr = 8 waves; wave owns 32 cols (2 frags); 4 m-frags (64 rows).
// X staged direct-to-LDS via global_load_lds, 1 row per wave-instr.
__global__ void __launch_bounds__(512, 4)
k_l1(const unsigned short* __restrict__ xbf,
     const unsigned short* __restrict__ w1f, const float* __restrict__ b1,
     const int* __restrict__ counts, const int* __restrict__ lists,
     unsigned short* __restrict__ hbuf) {
    __shared__ unsigned short lds[64 * D_IN];   // 64 KiB
    __shared__ int tl[64];

    int b = blockIdx.x;
    int e = b & 7;
    int rest = b >> 3;
    int tile = rest >> 1, ch = rest & 1;
    int cnt = counts[e];
    int row0 = tile * 64;
    if (row0 >= cnt) return;
    int rv = min(64, cnt - row0);
    int gb = row0;
    #pragma unroll
    for (int i = 0; i < 8; ++i) gb += (i < e) ? ((counts[i] + 63) & ~63) : 0;

    int tid = threadIdx.x, lane = tid & 63, wid = tid >> 6;
    int l15 = lane & 15, l4 = lane >> 4;
    if (tid < 64) tl[tid] = (tid < rv) ? lists[e * N_TOK + row0 + tid] : 0;

    const unsigned short* wbase = w1f + ((size_t)(e * 32 + ch * 16 + wid * 2) * 16) * 512 + (size_t)lane * 8;
    bf16x8 bb[3][2];
    #pragma unroll
    for (int n = 0; n < 2; ++n) {
        bb[0][n] = *(const bf16x8*)(wbase + (n * 16 + 0) * 512);
        bb[1][n] = *(const bf16x8*)(wbase + (n * 16 + 1) * 512);
    }
    float bv[2];
    #pragma unroll
    for (int n = 0; n < 2; ++n) bv[n] = b1[e * H_DIM + ch * 256 + wid * 32 + n * 16 + l15];
    __syncthreads();   // tl visible

    // stage X rows: wave w owns rows w*8..w*8+7; source-side XOR swizzle
    #pragma unroll
    for (int i = 0; i < 8; ++i) {
        int row = wid * 8 + i;
        if (row < rv) {
            int tok = tl[row] >> 1;
            const char* src = (const char*)xbf + ((size_t)tok << 10)
                            + ((lane * 16) ^ ((row & 7) << 4));
            gload_lds16(src, (char*)lds + row * 1024);
        } else {
            *(uint4*)((char*)lds + row * 1024 + lane * 16) = make_uint4(0, 0, 0, 0);
        }
    }
    __syncthreads();

    f32x4 acc[4][2];
    #pragma unroll
    for (int n = 0; n < 2; ++n)
        #pragma unroll
        for (int m = 0; m < 4; ++m) acc[m][n] = f32x4{bv[n], bv[n], bv[n], bv[n]};

    #pragma unroll
    for (int kc = 0; kc < 16; ++kc) {
        if (kc + 2 < 16) {
            #pragma unroll
            for (int n = 0; n < 2; ++n)
                bb[(kc + 2) % 3][n] = *(const bf16x8*)(wbase + (n * 16 + kc + 2) * 512);
        }
        int k0 = kc * 32 + l4 * 8;
        bf16x8 a[4];
        #pragma unroll
        for (int m = 0; m < 4; ++m) {
            int row = m * 16 + l15;
            int off = (row * 1024 + k0 * 2) ^ ((row & 7) << 4);
            a[m] = *(const bf16x8*)((const char*)lds + off);
        }
        #pragma unroll
        for (int n = 0; n < 2; ++n)
            #pragma unroll
            for (int m = 0; m < 4; ++m)
                acc[m][n] = __builtin_amdgcn_mfma_f32_16x16x32_bf16(a[m], bb[kc % 3][n], acc[m][n], 0, 0, 0);
    }
    __syncthreads();   // done reading A

    // gelu -> lds [64][256] linear
    #pragma unroll
    for (int m = 0; m < 4; ++m)
        #pragma unroll
        for (int n = 0; n < 2; ++n)
            #pragma unroll
            for (int r = 0; r < 4; ++r) {
                int row = m * 16 + l4 * 4 + r;
                int lcol = wid * 32 + n * 16 + l15;
                lds[row * 256 + lcol] = f2bf(gelu_exact(acc[m][n][r]));
            }
    __syncthreads();
    // coalesced H store
    #pragma unroll
    for (int it = 0; it < 4; ++it) {
        int idx = tid + it * 512;
        int row = idx >> 5, g = idx & 31;
        if (row < rv)
            *(uint4*)(hbuf + (size_t)(gb + row) * 512 + ch * 256 + g * 8) =
                *(uint4*)(lds + row * 256 + g * 8);
    }
}

// ---------- Layer 2: y = (H @ W2 + b2) * w -> ybuf slots ----------
template <bool SLOT>
__global__ void __launch_bounds__(512, 4)
k_l2(const unsigned short* __restrict__ hbuf,
     const unsigned short* __restrict__ w2f, const float* __restrict__ b2,
     const int* __restrict__ counts, const int* __restrict__ lists,
     const float* __restrict__ wgts,
     unsigned short* __restrict__ ybuf, float* __restrict__ out) {
    __shared__ unsigned short lds[64 * D_IN];   // 64 KiB
    __shared__ int   tl[64];
    __shared__ float wl[64];

    int b = blockIdx.x;
    int e = b & 7;
    int rest = b >> 3;
    int tile = rest >> 1, ch = rest & 1;
    int cnt = counts[e];
    int row0 = tile * 64;
    if (row0 >= cnt) return;
    int rv = min(64, cnt - row0);
    int gb = row0;
    #pragma unroll
    for (int i = 0; i < 8; ++i) gb += (i < e) ? ((counts[i] + 63) & ~63) : 0;

    int tid = threadIdx.x, lane = tid & 63, wid = tid >> 6;
    int l15 = lane & 15, l4 = lane >> 4;
    if (tid < 64) {
        int v = 0; float w = 0.f;
        if (tid < rv) {
            v = lists[e * N_TOK + row0 + tid];
            w = wgts [e * N_TOK + row0 + tid];
        }
        tl[tid] = v; wl[tid] = w;
    }

    const unsigned short* wbase = w2f + ((size_t)(e * 32 + ch * 16 + wid * 2) * 16) * 512 + (size_t)lane * 8;
    bf16x8 bb[3][2];
    #pragma unroll
    for (int n = 0; n < 2; ++n) {
        bb[0][n] = *(const bf16x8*)(wbase + (n * 16 + 0) * 512);
        bb[1][n] = *(const bf16x8*)(wbase + (n * 16 + 1) * 512);
    }
    float bv[2];
    #pragma unroll
    for (int n = 0; n < 2; ++n) bv[n] = b2[e * H_DIM + ch * 256 + wid * 32 + n * 16 + l15];
    __syncthreads();

    // stage H rows direct-to-LDS (pure bf16 copy, source-side swizzle)
    #pragma unroll
    for (int i = 0; i < 8; ++i) {
        int row = wid * 8 + i;
        if (row < rv) {
            const char* src = (const char*)hbuf + (((size_t)(gb + row)) << 10)
                            + ((lane * 16) ^ ((row & 7) << 4));
            gload_lds16(src, (char*)lds + row * 1024);
        } else {
            *(uint4*)((char*)lds + row * 1024 + lane * 16) = make_uint4(0, 0, 0, 0);
        }
    }
    __syncthreads();

    f32x4 acc[4][2];
    #pragma unroll
    for (int n = 0; n < 2; ++n)
        #pragma unroll
        for (int m = 0; m < 4; ++m) acc[m][n] = f32x4{bv[n], bv[n], bv[n], bv[n]};

    #pragma unroll
    for (int kc = 0; kc < 16; ++kc) {
        if (kc + 2 < 16) {
            #pragma unroll
            for (int n = 0; n < 2; ++n)
                bb[(kc + 2) % 3][n] = *(const bf16x8*)(wbase + (n * 16 + kc + 2) * 512);
        }
        int k0 = kc * 32 + l4 * 8;
        bf16x8 a[4];
        #pragma unroll
        for (int m = 0; m < 4; ++m) {
            int row = m * 16 + l15;
            int off = (row * 1024 + k0 * 2) ^ ((row & 7) << 4);
            a[m] = *(const bf16x8*)((const char*)lds + off);
        }
        #pragma unroll
        for (int n = 0; n < 2; ++n)
            #pragma unroll
            for (int m = 0; m < 4; ++m)
                acc[m][n] = __builtin_amdgcn_mfma_f32_16x16x32_bf16(a[m], bb[kc % 3][n], acc[m][n], 0, 0, 0);
    }

    if (SLOT) {
        __syncthreads();
        #pragma unroll
        for (int m = 0; m < 4; ++m)
            #pragma unroll
            for (int n = 0; n < 2; ++n)
                #pragma unroll
                for (int r = 0; r < 4; ++r) {
                    int row = m * 16 + l4 * 4 + r;
                    int lcol = wid * 32 + n * 16 + l15;
                    lds[row * 256 + lcol] = f2bf(acc[m][n][r] * wl[row]);
                }
        __syncthreads();
        #pragma unroll
        for (int it = 0; it < 4; ++it) {
            int idx = tid + it * 512;
            int row = idx >> 5, g = idx & 31;
            if (row < rv)
                *(uint4*)(ybuf + (size_t)tl[row] * 512 + ch * 256 + g * 8) =
                    *(uint4*)(lds + row * 256 + g * 8);
        }
    } else {
        #pragma unroll
        for (int m = 0; m < 4; ++m)
            #pragma unroll
            for (int r = 0; r < 4; ++r) {
                int row = m * 16 + l4 * 4 + r;
                if (row < rv) {
                    int t = tl[row] >> 1;
                    float gw = wl[row];
                    #pragma unroll
                    for (int n = 0; n < 2; ++n) {
                        int col = ch * 256 + wid * 32 + n * 16 + l15;
                        atomicAdd(out + (size_t)t * H_DIM + col, gw * acc[m][n][r]);
                    }
                }
            }
    }
}

// out[n][h] = yb[2n][h] + yb[2n+1][h]   (bf16 -> f32)
__global__ void __launch_bounds__(256) k_combine(const unsigned short* __restrict__ yb,
                                                 float* __restrict__ out) {
    int gid = blockIdx.x * 256 + threadIdx.x;
    int n = gid >> 6;
    int h0 = (gid & 63) * 8;
    const unsigned short* r0 = yb + ((size_t)2 * n) * H_DIM + h0;
    uint4 a = *(const uint4*)r0;
    uint4 b = *(const uint4*)(r0 + H_DIM);
    float o[8];
    unsigned ua[4] = {a.x, a.y, a.z, a.w}, ub[4] = {b.x, b.y, b.z, b.w};
    #pragma unroll
    for (int j = 0; j < 4; ++j) {
        o[2 * j]     = bf2f((unsigned short)(ua[j] & 0xFFFF)) + bf2f((unsigned short)(ub[j] & 0xFFFF));
        o[2 * j + 1] = bf2f((unsigned short)(ua[j] >> 16))    + bf2f((unsigned short)(ub[j] >> 16));
    }
    float* dst = out + (size_t)n * H_DIM + h0;
    *(float4*)dst       = make_float4(o[0], o[1], o[2], o[3]);
    *(float4*)(dst + 4) = make_float4(o[4], o[5], o[6], o[7]);
}

extern "C" void kernel_launch(void* const* d_in, const int* in_sizes, int n_in,
                              void* d_out, int out_size, void* d_ws, size_t ws_size,
                              hipStream_t stream) {
    (void)in_sizes; (void)n_in;
    const float* x  = (const float*)d_in[0];
    const float* Wg = (const float*)d_in[1];
    const float* bg = (const float*)d_in[2];
    const float* W1 = (const float*)d_in[3];
    const float* b1 = (const float*)d_in[4];
    const float* W2 = (const float*)d_in[5];
    const float* b2 = (const float*)d_in[6];
    float* out = (float*)d_out;

    char* ws = (char*)d_ws;
    const size_t tail_sz = 256 + 262144 + 262144 + 8192 + 65536;
    size_t need1 = (49ull << 20) + tail_sz;   // full slot path
    size_t need2 = (33ull << 20) + tail_sz;   // de-fused, atomic L2

    unsigned short* w1f = (unsigned short*)(ws);                 // 4 MiB
    unsigned short* w2f = (unsigned short*)(ws + (4ull << 20));  // 4 MiB
    unsigned short* ybuf = nullptr;
    unsigned short* hbuf = nullptr;
    unsigned short* xbf  = nullptr;
    char* tail;
    int mode;
    if (ws_size >= need1) {
        mode = 0;
        ybuf = (unsigned short*)(ws + (8ull << 20));             // 16 MiB
        hbuf = (unsigned short*)(ws + (24ull << 20));            // 17 MiB
        xbf  = (unsigned short*)(ws + (41ull << 20));            // 8 MiB
        tail = ws + (49ull << 20);
    } else {
        mode = 1;
        hbuf = (unsigned short*)(ws + (8ull << 20));             // 17 MiB
        xbf  = (unsigned short*)(ws + (25ull << 20));            // 8 MiB
        tail = ws + (33ull << 20);
    }
    int*   counts = (int*)(tail);
    int*   lists  = (int*)(tail + 256);
    float* wgts   = (float*)(tail + 256 + 262144);
    unsigned char* sel = (unsigned char*)(tail + 256 + 524288);
    float2* w2g   = (float2*)(tail + 256 + 532480);

    if (mode == 1)
        hipMemsetAsync(out, 0, (size_t)out_size * sizeof(float), stream);

    k_pack<<<dim3(8, 16, 16), dim3(256), 0, stream>>>(W1, W2, w1f, w2f);
    k_gate<<<dim3(N_TOK / 32), dim3(256), 0, stream>>>(x, Wg, bg, sel, w2g, xbf);
    k_build<<<dim3(N_EXP), dim3(1024), 0, stream>>>(sel, w2g, counts, lists, wgts);
    k_l1<<<dim3(2048), dim3(512), 0, stream>>>(xbf, w1f, b1, counts, lists, hbuf);
    if (mode == 0) {
        k_l2<true><<<dim3(2048), dim3(512), 0, stream>>>(
            hbuf, w2f, b2, counts, lists, wgts, ybuf, out);
        k_combine<<<dim3(N_TOK * 64 / 256), dim3(256), 0, stream>>>(ybuf, out);
    } else {
        k_l2<false><<<dim3(2048), dim3(512), 0, stream>>>(
            hbuf, w2f, b2, counts, lists, wgts, hbuf /*unused*/, out);
    }
}

// Round 10
// 164.127 us; speedup vs baseline: 1.2692x; 1.0268x over previous
//
#include <hip/hip_runtime.h>
#include <hip/hip_bf16.h>

// MoE: B=4,T=2048,D=512,E=8,H=512,K=2.  N=8192 tokens.
// v10: v9 + (a) k_build with 2 barriers instead of 24 (ballots in regs,
// 2-level prefix), (b) depth-3 ring-4 B prefetch in k_l1/k_l2.

typedef __bf16 bf16x8 __attribute__((ext_vector_type(8)));
typedef float  f32x4  __attribute__((ext_vector_type(4)));

#define N_TOK 8192
#define D_IN  512
#define N_EXP 8
#define H_DIM 512

static __device__ __forceinline__ unsigned short f2bf(float f) {
    union { float f; unsigned u; } v; v.f = f;
    unsigned r = v.u + 0x7FFFu + ((v.u >> 16) & 1u);   // RNE
    return (unsigned short)(r >> 16);
}
static __device__ __forceinline__ float bf2f(unsigned short h) {
    union { unsigned u; float f; } v; v.u = ((unsigned)h) << 16; return v.f;
}
static __device__ __forceinline__ float gelu_exact(float v) {
    return 0.5f * v * (1.0f + erff(v * 0.70710678118654752f));
}
// direct global->LDS copy, 16B per lane (wave stages 1 KiB row)
static __device__ __forceinline__ void gload_lds16(const void* src, void* lds_dst) {
    __builtin_amdgcn_global_load_lds(
        (const __attribute__((address_space(1))) unsigned int*)src,
        (__attribute__((address_space(3))) unsigned int*)lds_dst, 16, 0, 0);
}

// Pack W1 and W2 (f32 [E][512][512]) into MFMA B-fragment-linear bf16:
// out[((e*32+cb)*16+kc)*512 + lane*8 + j] = bf16(W[e][kc*32+(lane>>4)*8+j][cb*16+(lane&15)])
__global__ void __launch_bounds__(256) k_pack(const float* __restrict__ W1,
                                              const float* __restrict__ W2,
                                              unsigned short* __restrict__ w1f,
                                              unsigned short* __restrict__ w2f) {
    __shared__ float t[32][65];
    int z = blockIdx.z;
    int e = z & 7;
    const float* in = (z < 8) ? W1 : W2;
    unsigned short* out = (z < 8) ? w1f : w2f;
    int cb0 = blockIdx.x * 4;
    int kc  = blockIdx.y;
    const float* src = in + ((size_t)e * 512 + kc * 32) * 512 + blockIdx.x * 64;
    int tid = threadIdx.x;
    int r = tid >> 3, cq = (tid & 7) * 8;
    float4 v0 = *(const float4*)(src + (size_t)r * 512 + cq);
    float4 v1 = *(const float4*)(src + (size_t)r * 512 + cq + 4);
    t[r][cq + 0] = v0.x; t[r][cq + 1] = v0.y; t[r][cq + 2] = v0.z; t[r][cq + 3] = v0.w;
    t[r][cq + 4] = v1.x; t[r][cq + 5] = v1.y; t[r][cq + 6] = v1.z; t[r][cq + 7] = v1.w;
    __syncthreads();
    int g = tid >> 6, lane = tid & 63;
    int l15 = lane & 15, l4 = lane >> 4;
    unsigned v[4];
    #pragma unroll
    for (int j = 0; j < 4; ++j) {
        unsigned lo = f2bf(t[l4 * 8 + 2 * j    ][g * 16 + l15]);
        unsigned hi = f2bf(t[l4 * 8 + 2 * j + 1][g * 16 + l15]);
        v[j] = lo | (hi << 16);
    }
    size_t dst = (((size_t)(e * 32 + cb0 + g) * 16 + kc) * 512) + lane * 8;
    *(uint4*)(out + dst) = make_uint4(v[0], v[1], v[2], v[3]);
}

// Gate: block = 256 thr = 32 tokens. Thread (t,c) owns 64-elem chunk c of
// token t's row: x read ONCE, coalesced. Partial dots -> LDS reduce -> top-2.
// Phase 2: convert the block's 32 rows to bf16 (xbf), coalesced.
__global__ void __launch_bounds__(256) k_gate(const float* __restrict__ x,
                                              const float* __restrict__ Wg,
                                              const float* __restrict__ bg,
                                              unsigned char* __restrict__ sel,
                                              float2* __restrict__ w2,
                                              unsigned short* __restrict__ xbf) {
    __shared__ float part[32][8][8];
    __shared__ float lg[32][8];
    int tid = threadIdx.x;
    int t = tid >> 3, c = tid & 7;
    int n0 = blockIdx.x * 32;
    int n = n0 + t;
    const float4* xr = (const float4*)(x + (size_t)n * D_IN + c * 64);
    float acc[8];
    #pragma unroll
    for (int e = 0; e < 8; ++e) acc[e] = 0.f;
    #pragma unroll
    for (int j4 = 0; j4 < 16; ++j4) {
        float4 v = xr[j4];
        int k = c * 64 + j4 * 4;
        float xv[4] = {v.x, v.y, v.z, v.w};
        #pragma unroll
        for (int u = 0; u < 4; ++u) {
            float4 wlo = *(const float4*)(Wg + (size_t)(k + u) * 8);
            float4 whi = *(const float4*)(Wg + (size_t)(k + u) * 8 + 4);
            acc[0] += xv[u] * wlo.x; acc[1] += xv[u] * wlo.y;
            acc[2] += xv[u] * wlo.z; acc[3] += xv[u] * wlo.w;
            acc[4] += xv[u] * whi.x; acc[5] += xv[u] * whi.y;
            acc[6] += xv[u] * whi.z; acc[7] += xv[u] * whi.w;
        }
    }
    #pragma unroll
    for (int e = 0; e < 8; ++e) part[t][c][e] = acc[e];
    __syncthreads();
    {
        float f = bg[c];
        #pragma unroll
        for (int cc = 0; cc < 8; ++cc) f += part[t][cc][c];
        lg[t][c] = f;
    }
    __syncthreads();
    if (c == 0) {
        float best = lg[t][0]; int i1 = 0;
        #pragma unroll
        for (int j = 1; j < 8; ++j) { float v = lg[t][j]; if (v > best) { best = v; i1 = j; } }
        float best2 = -1e30f; int i2 = 0;
        #pragma unroll
        for (int j = 0; j < 8; ++j) {
            if (j == i1) continue;
            float v = lg[t][j]; if (v > best2) { best2 = v; i2 = j; }
        }
        float tt = expf(best2 - best);
        float w0 = 1.0f / (1.0f + tt);
        sel[n] = (unsigned char)(i1 | (i2 << 4));
        w2[n] = make_float2(w0, 1.0f - w0);
    }
    // phase 2: f32 -> bf16 copy of this block's 32 rows (reads hit L1/L2)
    #pragma unroll
    for (int i = 0; i < 8; ++i) {
        int idx = tid + i * 256;
        int r = idx >> 6, g = idx & 63;
        const float* src = x + (size_t)(n0 + r) * D_IN + g * 8;
        float4 a = *(const float4*)src;
        float4 b = *(const float4*)(src + 4);
        unsigned u0 = (unsigned)f2bf(a.x) | ((unsigned)f2bf(a.y) << 16);
        unsigned u1 = (unsigned)f2bf(a.z) | ((unsigned)f2bf(a.w) << 16);
        unsigned u2 = (unsigned)f2bf(b.x) | ((unsigned)f2bf(b.y) << 16);
        unsigned u3 = (unsigned)f2bf(b.z) | ((unsigned)f2bf(b.w) << 16);
        *(uint4*)(xbf + (size_t)(n0 + r) * D_IN + g * 8) = make_uint4(u0, u1, u2, u3);
    }
}

// Build per-expert compacted token lists.  All 8 chunk-ballots up front
// (registers), 2-level prefix, 2 barriers total.  Deterministic.
// lists entry = (token<<1) | slot  (slot 0 = top1, 1 = top2).
__global__ void __launch_bounds__(1024) k_build(const unsigned char* __restrict__ sel,
                                                const float2* __restrict__ w2,
                                                int* __restrict__ counts,
                                                int* __restrict__ lists,
                                                float* __restrict__ wgts) {
    int e = blockIdx.x;
    __shared__ int tot[8][16];
    __shared__ int cbase[8];
    int tid = threadIdx.x, lane = tid & 63, wv = tid >> 6;
    unsigned long long masks[8];
    unsigned char svals[8];
    #pragma unroll
    for (int c = 0; c < 8; ++c) {
        int n = c * 1024 + tid;
        unsigned char s = sel[n];
        svals[c] = s;
        bool f = ((s & 15) == e) || ((s >> 4) == e);
        masks[c] = __ballot(f);
        if (lane == 0) tot[c][wv] = __popcll(masks[c]);
    }
    __syncthreads();
    if (tid == 0) {
        int b = 0;
        #pragma unroll
        for (int c = 0; c < 8; ++c) {
            cbase[c] = b;
            #pragma unroll
            for (int i = 0; i < 16; ++i) b += tot[c][i];
        }
        counts[e] = b;
    }
    __syncthreads();
    #pragma unroll
    for (int c = 0; c < 8; ++c) {
        if ((masks[c] >> lane) & 1ull) {
            int wb = cbase[c];
            for (int i = 0; i < wv; ++i) wb += tot[c][i];
            int pos = wb + __popcll(masks[c] & ((1ull << lane) - 1ull));
            int n = c * 1024 + tid;
            bool f1 = ((svals[c] & 15) == e);
            lists[e * N_TOK + pos] = (n << 1) | (f1 ? 0 : 1);
            float2 w = w2[n];
            wgts[e * N_TOK + pos] = f1 ? w.x : w.y;
        }
    }
}

// ---------- Layer 1: H = gelu(X @ W1 + b1), 64x256 tiles ----------
// grid flat: e = b&7 (XCD affinity), tile = (b>>3)>>1, ch = (b>>3)&1.
// 512 thr = 8 waves; wave owns 32 cols (2 frags); 4 m-frags (64 rows).
// X staged direct-to-LDS via global_load_lds; depth-3 ring-4 B prefetch.
__global__ void __launch_bounds__(512, 4)
k_l1(const unsigned short* __restrict__ xbf,
     const unsigned short* __restrict__ w1f, const float* __restrict__ b1,
     const int* __restrict__ counts, const int* __restrict__ lists,
     unsigned short* __restrict__ hbuf) {
    __shared__ unsigned short lds[64 * D_IN];   // 64 KiB
    __shared__ int tl[64];

    int b = blockIdx.x;
    int e = b & 7;
    int rest = b >> 3;
    int tile = rest >> 1, ch = rest & 1;
    int cnt = counts[e];
    int row0 = tile * 64;
    if (row0 >= cnt) return;
    int rv = min(64, cnt - row0);
    int gb = row0;
    #pragma unroll
    for (int i = 0; i < 8; ++i) gb += (i < e) ? ((counts[i] + 63) & ~63) : 0;

    int tid = threadIdx.x, lane = tid & 63, wid = tid >> 6;
    int l15 = lane & 15, l4 = lane >> 4;
    if (tid < 64) tl[tid] = (tid < rv) ? lists[e * N_TOK + row0 + tid] : 0;

    const unsigned short* wbase = w1f + ((size_t)(e * 32 + ch * 16 + wid * 2) * 16) * 512 + (size_t)lane * 8;
    bf16x8 bb[4][2];
    #pragma unroll
    for (int n = 0; n < 2; ++n) {
        bb[0][n] = *(const bf16x8*)(wbase + (n * 16 + 0) * 512);
        bb[1][n] = *(const bf16x8*)(wbase + (n * 16 + 1) * 512);
        bb[2][n] = *(const bf16x8*)(wbase + (n * 16 + 2) * 512);
    }
    float bv[2];
    #pragma unroll
    for (int n = 0; n < 2; ++n) bv[n] = b1[e * H_DIM + ch * 256 + wid * 32 + n * 16 + l15];
    __syncthreads();   // tl visible

    // stage X rows: wave w owns rows w*8..w*8+7; source-side XOR swizzle
    #pragma unroll
    for (int i = 0; i < 8; ++i) {
        int row = wid * 8 + i;
        if (row < rv) {
            int tok = tl[row] >> 1;
            const char* src = (const char*)xbf + ((size_t)tok << 10)
                            + ((lane * 16) ^ ((row & 7) << 4));
            gload_lds16(src, (char*)lds + row * 1024);
        } else {
            *(uint4*)((char*)lds + row * 1024 + lane * 16) = make_uint4(0, 0, 0, 0);
        }
    }
    __syncthreads();

    f32x4 acc[4][2];
    #pragma unroll
    for (int n = 0; n < 2; ++n)
        #pragma unroll
        for (int m = 0; m < 4; ++m) acc[m][n] = f32x4{bv[n], bv[n], bv[n], bv[n]};

    #pragma unroll
    for (int kc = 0; kc < 16; ++kc) {
        if (kc + 3 < 16) {
            #pragma unroll
            for (int n = 0; n < 2; ++n)
                bb[(kc + 3) & 3][n] = *(const bf16x8*)(wbase + (n * 16 + kc + 3) * 512);
        }
        int k0 = kc * 32 + l4 * 8;
        bf16x8 a[4];
        #pragma unroll
        for (int m = 0; m < 4; ++m) {
            int row = m * 16 + l15;
            int off = (row * 1024 + k0 * 2) ^ ((row & 7) << 4);
            a[m] = *(const bf16x8*)((const char*)lds + off);
        }
        #pragma unroll
        for (int n = 0; n < 2; ++n)
            #pragma unroll
            for (int m = 0; m < 4; ++m)
                acc[m][n] = __builtin_amdgcn_mfma_f32_16x16x32_bf16(a[m], bb[kc & 3][n], acc[m][n], 0, 0, 0);
    }
    __syncthreads();   // done reading A

    // gelu -> lds [64][256] linear
    #pragma unroll
    for (int m = 0; m < 4; ++m)
        #pragma unroll
        for (int n = 0; n < 2; ++n)
            #pragma unroll
            for (int r = 0; r < 4; ++r) {
                int row = m * 16 + l4 * 4 + r;
                int lcol = wid * 32 + n * 16 + l15;
                lds[row * 256 + lcol] = f2bf(gelu_exact(acc[m][n][r]));
            }
    __syncthreads();
    // coalesced H store
    #pragma unroll
    for (int it = 0; it < 4; ++it) {
        int idx = tid + it * 512;
        int row = idx >> 5, g = idx & 31;
        if (row < rv)
            *(uint4*)(hbuf + (size_t)(gb + row) * 512 + ch * 256 + g * 8) =
                *(uint4*)(lds + row * 256 + g * 8);
    }
}

// ---------- Layer 2: y = (H @ W2 + b2) * w -> ybuf slots ----------
template <bool SLOT>
__global__ void __launch_bounds__(512, 4)
k_l2(const unsigned short* __restrict__ hbuf,
     const unsigned short* __restrict__ w2f, const float* __restrict__ b2,
     const int* __restrict__ counts, const int* __restrict__ lists,
     const float* __restrict__ wgts,
     unsigned short* __restrict__ ybuf, float* __restrict__ out) {
    __shared__ unsigned short lds[64 * D_IN];   // 64 KiB
    __shared__ int   tl[64];
    __shared__ float wl[64];

    int b = blockIdx.x;
    int e = b & 7;
    int rest = b >> 3;
    int tile = rest >> 1, ch = rest & 1;
    int cnt = counts[e];
    int row0 = tile * 64;
    if (row0 >= cnt) return;
    int rv = min(64, cnt - row0);
    int gb = row0;
    #pragma unroll
    for (int i = 0; i < 8; ++i) gb += (i < e) ? ((counts[i] + 63) & ~63) : 0;

    int tid = threadIdx.x, lane = tid & 63, wid = tid >> 6;
    int l15 = lane & 15, l4 = lane >> 4;
    if (tid < 64) {
        int v = 0; float w = 0.f;
        if (tid < rv) {
            v = lists[e * N_TOK + row0 + tid];
            w = wgts [e * N_TOK + row0 + tid];
        }
        tl[tid] = v; wl[tid] = w;
    }

    const unsigned short* wbase = w2f + ((size_t)(e * 32 + ch * 16 + wid * 2) * 16) * 512 + (size_t)lane * 8;
    bf16x8 bb[4][2];
    #pragma unroll
    for (int n = 0; n < 2; ++n) {
        bb[0][n] = *(const bf16x8*)(wbase + (n * 16 + 0) * 512);
        bb[1][n] = *(const bf16x8*)(wbase + (n * 16 + 1) * 512);
        bb[2][n] = *(const bf16x8*)(wbase + (n * 16 + 2) * 512);
    }
    float bv[2];
    #pragma unroll
    for (int n = 0; n < 2; ++n) bv[n] = b2[e * H_DIM + ch * 256 + wid * 32 + n * 16 + l15];
    __syncthreads();

    // stage H rows direct-to-LDS (pure bf16 copy, source-side swizzle)
    #pragma unroll
    for (int i = 0; i < 8; ++i) {
        int row = wid * 8 + i;
        if (row < rv) {
            const char* src = (const char*)hbuf + (((size_t)(gb + row)) << 10)
                            + ((lane * 16) ^ ((row & 7) << 4));
            gload_lds16(src, (char*)lds + row * 1024);
        } else {
            *(uint4*)((char*)lds + row * 1024 + lane * 16) = make_uint4(0, 0, 0, 0);
        }
    }
    __syncthreads();

    f32x4 acc[4][2];
    #pragma unroll
    for (int n = 0; n < 2; ++n)
        #pragma unroll
        for (int m = 0; m < 4; ++m) acc[m][n] = f32x4{bv[n], bv[n], bv[n], bv[n]};

    #pragma unroll
    for (int kc = 0; kc < 16; ++kc) {
        if (kc + 3 < 16) {
            #pragma unroll
            for (int n = 0; n < 2; ++n)
                bb[(kc + 3) & 3][n] = *(const bf16x8*)(wbase + (n * 16 + kc + 3) * 512);
        }
        int k0 = kc * 32 + l4 * 8;
        bf16x8 a[4];
        #pragma unroll
        for (int m = 0; m < 4; ++m) {
            int row = m * 16 + l15;
            int off = (row * 1024 + k0 * 2) ^ ((row & 7) << 4);
            a[m] = *(const bf16x8*)((const char*)lds + off);
        }
        #pragma unroll
        for (int n = 0; n < 2; ++n)
            #pragma unroll
            for (int m = 0; m < 4; ++m)
                acc[m][n] = __builtin_amdgcn_mfma_f32_16x16x32_bf16(a[m], bb[kc & 3][n], acc[m][n], 0, 0, 0);
    }

    if (SLOT) {
        __syncthreads();
        #pragma unroll
        for (int m = 0; m < 4; ++m)
            #pragma unroll
            for (int n = 0; n < 2; ++n)
                #pragma unroll
                for (int r = 0; r < 4; ++r) {
                    int row = m * 16 + l4 * 4 + r;
                    int lcol = wid * 32 + n * 16 + l15;
                    lds[row * 256 + lcol] = f2bf(acc[m][n][r] * wl[row]);
                }
        __syncthreads();
        #pragma unroll
        for (int it = 0; it < 4; ++it) {
            int idx = tid + it * 512;
            int row = idx >> 5, g = idx & 31;
            if (row < rv)
                *(uint4*)(ybuf + (size_t)tl[row] * 512 + ch * 256 + g * 8) =
                    *(uint4*)(lds + row * 256 + g * 8);
        }
    } else {
        #pragma unroll
        for (int m = 0; m < 4; ++m)
            #pragma unroll
            for (int r = 0; r < 4; ++r) {
                int row = m * 16 + l4 * 4 + r;
                if (row < rv) {
                    int t = tl[row] >> 1;
                    float gw = wl[row];
                    #pragma unroll
                    for (int n = 0; n < 2; ++n) {
                        int col = ch * 256 + wid * 32 + n * 16 + l15;
                        atomicAdd(out + (size_t)t * H_DIM + col, gw * acc[m][n][r]);
                    }
                }
            }
    }
}

// out[n][h] = yb[2n][h] + yb[2n+1][h]   (bf16 -> f32)
__global__ void __launch_bounds__(256) k_combine(const unsigned short* __restrict__ yb,
                                                 float* __restrict__ out) {
    int gid = blockIdx.x * 256 + threadIdx.x;
    int n = gid >> 6;
    int h0 = (gid & 63) * 8;
    const unsigned short* r0 = yb + ((size_t)2 * n) * H_DIM + h0;
    uint4 a = *(const uint4*)r0;
    uint4 b = *(const uint4*)(r0 + H_DIM);
    float o[8];
    unsigned ua[4] = {a.x, a.y, a.z, a.w}, ub[4] = {b.x, b.y, b.z, b.w};
    #pragma unroll
    for (int j = 0; j < 4; ++j) {
        o[2 * j]     = bf2f((unsigned short)(ua[j] & 0xFFFF)) + bf2f((unsigned short)(ub[j] & 0xFFFF));
        o[2 * j + 1] = bf2f((unsigned short)(ua[j] >> 16))    + bf2f((unsigned short)(ub[j] >> 16));
    }
    float* dst = out + (size_t)n * H_DIM + h0;
    *(float4*)dst       = make_float4(o[0], o[1], o[2], o[3]);
    *(float4*)(dst + 4) = make_float4(o[4], o[5], o[6], o[7]);
}

extern "C" void kernel_launch(void* const* d_in, const int* in_sizes, int n_in,
                              void* d_out, int out_size, void* d_ws, size_t ws_size,
                              hipStream_t stream) {
    (void)in_sizes; (void)n_in;
    const float* x  = (const float*)d_in[0];
    const float* Wg = (const float*)d_in[1];
    const float* bg = (const float*)d_in[2];
    const float* W1 = (const float*)d_in[3];
    const float* b1 = (const float*)d_in[4];
    const float* W2 = (const float*)d_in[5];
    const float* b2 = (const float*)d_in[6];
    float* out = (float*)d_out;

    char* ws = (char*)d_ws;
    const size_t tail_sz = 256 + 262144 + 262144 + 8192 + 65536;
    size_t need1 = (49ull << 20) + tail_sz;   // full slot path
    size_t need2 = (33ull << 20) + tail_sz;   // de-fused, atomic L2

    unsigned short* w1f = (unsigned short*)(ws);                 // 4 MiB
    unsigned short* w2f = (unsigned short*)(ws + (4ull << 20));  // 4 MiB
    unsigned short* ybuf = nullptr;
    unsigned short* hbuf = nullptr;
    unsigned short* xbf  = nullptr;
    char* tail;
    int mode;
    if (ws_size >= need1) {
        mode = 0;
        ybuf = (unsigned short*)(ws + (8ull << 20));             // 16 MiB
        hbuf = (unsigned short*)(ws + (24ull << 20));            // 17 MiB
        xbf  = (unsigned short*)(ws + (41ull << 20));            // 8 MiB
        tail = ws + (49ull << 20);
    } else {
        mode = 1;
        hbuf = (unsigned short*)(ws + (8ull << 20));             // 17 MiB
        xbf  = (unsigned short*)(ws + (25ull << 20));            // 8 MiB
        tail = ws + (33ull << 20);
    }
    int*   counts = (int*)(tail);
    int*   lists  = (int*)(tail + 256);
    float* wgts   = (float*)(tail + 256 + 262144);
    unsigned char* sel = (unsigned char*)(tail + 256 + 524288);
    float2* w2g   = (float2*)(tail + 256 + 532480);

    if (mode == 1)
        hipMemsetAsync(out, 0, (size_t)out_size * sizeof(float), stream);

    k_pack<<<dim3(8, 16, 16), dim3(256), 0, stream>>>(W1, W2, w1f, w2f);
    k_gate<<<dim3(N_TOK / 32), dim3(256), 0, stream>>>(x, Wg, bg, sel, w2g, xbf);
    k_build<<<dim3(N_EXP), dim3(1024), 0, stream>>>(sel, w2g, counts, lists, wgts);
    k_l1<<<dim3(2048), dim3(512), 0, stream>>>(xbf, w1f, b1, counts, lists, hbuf);
    if (mode == 0) {
        k_l2<true><<<dim3(2048), dim3(512), 0, stream>>>(
            hbuf, w2f, b2, counts, lists, wgts, ybuf, out);
        k_combine<<<dim3(N_TOK * 64 / 256), dim3(256), 0, stream>>>(ybuf, out);
    } else {
        k_l2<false><<<dim3(2048), dim3(512), 0, stream>>>(
            hbuf, w2f, b2, counts, lists, wgts, hbuf /*unused*/, out);
    }
}